// Round 4
// baseline (259.039 us; speedup 1.0000x reference)
//
#include <hip/hip_runtime.h>

#define NROWS  16384
#define DIM    2048
#define KSEL   64          // TOPK/2 per side
#define FACTOR 6.26f
#define CAP    256         // per-side tie-candidate capacity (tie bin ~50, huge margin)
#define TPB    128
#define EPT    16          // elements per thread

typedef float v4f __attribute__((ext_vector_type(4)));

// Monotone order-preserving float->uint transform:
// ascending x  <=>  ascending u ; all negatives < all positives.
__device__ __forceinline__ unsigned f2ord(float f) {
    unsigned b = __float_as_uint(f);
    unsigned m = ((unsigned)((int)b >> 31)) | 0x80000000u;
    return b ^ m;
}

__global__ __launch_bounds__(TPB, 8)
void kcomp_kernel(const float* __restrict__ xin, float* __restrict__ out)
{
    __shared__ unsigned hist32[1024];   // 2048 u16 bins packed in pairs (4 KB)
    __shared__ unsigned cand[2][CAP];   // packed (keyLow21<<11)|(2047-idx)
    __shared__ int      cnt[2];
    __shared__ int      shd[8];         // P: D,need,eqc,cut @0..3 ; N: @4..7
    __shared__ unsigned wsum0;
    __shared__ float    redf[4];        // lp0,lp1,ln0,ln1

    const int tid  = threadIdx.x;
    const int lane = tid & 63;
    const int wid  = tid >> 6;
    const size_t rowbase = (size_t)blockIdx.x * DIM;
    const float4* pin = (const float4*)(xin + rowbase);

    // thread t owns consecutive elements [16t, 16t+16)
    float xv[EPT]; unsigned u[EPT];
    #pragma unroll
    for (int q = 0; q < 4; ++q) {
        float4 v = pin[4 * tid + q];
        xv[4*q+0] = v.x; xv[4*q+1] = v.y; xv[4*q+2] = v.z; xv[4*q+3] = v.w;
    }
    #pragma unroll
    for (int e = 0; e < EPT; ++e) u[e] = f2ord(xv[e]);

    // ---- clear ----
    const uint4 z4 = {0u, 0u, 0u, 0u};
    ((uint4*)hist32)[tid]       = z4;
    ((uint4*)hist32)[tid + 128] = z4;
    if (tid < 2) cnt[tid] = 0;
    if (tid < 8) shd[tid] = 0;
    __syncthreads();

    // ---- single histogram pass: 11-bit digit (u>>21), serves BOTH sides ----
    #pragma unroll
    for (int e = 0; e < EPT; ++e) {
        unsigned d = u[e] >> 21;
        atomicAdd(&hist32[d >> 1], 1u << ((d & 1u) << 4));
    }
    __syncthreads();

    // ---- scan: thread t owns bins [16t,16t+16) = words [8t,8t+8) ----
    uint4 h0 = ((const uint4*)hist32)[2 * tid];
    uint4 h1 = ((const uint4*)hist32)[2 * tid + 1];
    unsigned L =
        (h0.x & 0xffffu) + (h0.x >> 16) + (h0.y & 0xffffu) + (h0.y >> 16) +
        (h0.z & 0xffffu) + (h0.z >> 16) + (h0.w & 0xffffu) + (h0.w >> 16) +
        (h1.x & 0xffffu) + (h1.x >> 16) + (h1.y & 0xffffu) + (h1.y >> 16) +
        (h1.z & 0xffffu) + (h1.z >> 16) + (h1.w & 0xffffu) + (h1.w >> 16);
    unsigned sc = L;
    #pragma unroll
    for (int off = 1; off < 64; off <<= 1) {
        unsigned v = __shfl_up(sc, off);
        if (lane >= off) sc += v;
    }
    if (tid == 63) wsum0 = sc;          // wave-0 total
    __syncthreads();
    const unsigned base = sc - L + (wid ? wsum0 : 0u);

    // ---- crossing walk: only the straddling thread(s) ----
    {
        const unsigned TN = KSEL;               // bottom-64 crossing
        const unsigned TP = DIM - KSEL + 1;     // top-64 crossing (1985)
        const unsigned hiB = base + L;
        if ((base < TN && TN <= hiB) || (base < TP && TP <= hiB)) {
            unsigned w[8] = {h0.x, h0.y, h0.z, h0.w, h1.x, h1.y, h1.z, h1.w};
            unsigned acc = base;
            #pragma unroll
            for (int i = 0; i < 16; ++i) {
                unsigned h = (i & 1) ? (w[i >> 1] >> 16) : (w[i >> 1] & 0xffffu);
                unsigned acc2 = acc + h;
                if (acc < TN && TN <= acc2) { shd[4] = (tid << 4) | i; shd[5] = (int)(TN - acc);        shd[6] = (int)h; }
                if (acc < TP && TP <= acc2) { shd[0] = (tid << 4) | i; shd[1] = (int)(acc2 - (TP - 1)); shd[2] = (int)h; }
                acc = acc2;
            }
        }
    }
    __syncthreads();
    const int Dp = shd[0], needP = shd[1], eqcP = shd[2];
    const int Dn = shd[4], needN = shd[5], eqcN = shd[6];
    const bool fastP = (eqcP == needP);
    const bool fastN = (eqcN == needN);
    const unsigned tieLoP = (unsigned)Dp << 21;
    const unsigned tieLoN = (unsigned)Dn << 21;
    unsigned long long h64;
    h64 = ((unsigned long long)(Dp + 1)) << 21;
    const unsigned hiP = (h64 > 0xFFFFFFFFull) ? 0xFFFFFFFFu : (unsigned)h64;
    h64 = ((unsigned long long)(Dn + 1)) << 21;
    const unsigned hiN = (h64 > 0xFFFFFFFFull) ? 0xFFFFFFFFu : (unsigned)h64;
    const unsigned thrP = fastP ? tieLoP : hiP;      // plain winners: u >= thrP
    const unsigned thrN = fastN ? hiN   : tieLoN;    // plain winners: u <  thrN
    const unsigned tieLenP = fastP ? 0u : 0x200000u;
    const unsigned tieLenN = fastN ? 0u : 0x200000u;

    // ---- gather tie candidates (packed keys are unique -> exact tie-break) ----
    #pragma unroll
    for (int e = 0; e < EPT; ++e) {
        const unsigned idx = (unsigned)((tid << 4) | e);
        if (u[e] - tieLoP < tieLenP) {
            int s = atomicAdd(&cnt[0], 1);
            if (s < CAP) cand[0][s] = ((u[e] & 0x1FFFFFu) << 11) | (2047u - idx);
        }
        if (u[e] - tieLoN < tieLenN) {
            int s = atomicAdd(&cnt[1], 1);
            if (s < CAP) cand[1][s] = (((~u[e]) & 0x1FFFFFu) << 11) | (2047u - idx);
        }
    }
    __syncthreads();

    // ---- rank: wave0 -> P, wave1 -> N; publish the need-th largest as cut ----
    {
        const int side = wid;
        const bool fast = side ? fastN : fastP;
        if (!fast) {
            const int eqc  = side ? eqcN : eqcP;
            const int need = side ? needN : needP;
            const int ec   = min(eqc, CAP);
            for (int j = lane; j < ec; j += 64) {
                const unsigned mine = cand[side][j];
                int rank = 0;
                for (int s = 0; s < ec; ++s)      // broadcast LDS reads
                    rank += (cand[side][s] > mine);
                if (rank == need - 1) shd[side ? 7 : 3] = (int)mine;
            }
        }
    }
    __syncthreads();
    const unsigned cutP = (unsigned)shd[3];
    const unsigned cutN = (unsigned)shd[7];

    // ---- energy: loser sums (tie winners corrected via cut test) ----
    float lp = 0.f, ln = 0.f;
    #pragma unroll
    for (int e = 0; e < EPT; ++e) {
        const float px = fmaxf(xv[e], 0.f);
        const float nx = px - xv[e];             // == fmaxf(-x, 0)
        const unsigned idx = (unsigned)((tid << 4) | e);
        bool wP = (u[e] >= thrP);
        bool wN = (u[e] <  thrN);
        if (u[e] - tieLoP < tieLenP) {
            unsigned pk = ((u[e] & 0x1FFFFFu) << 11) | (2047u - idx);
            if (pk >= cutP) wP = true;
        }
        if (u[e] - tieLoN < tieLenN) {
            unsigned pk = (((~u[e]) & 0x1FFFFFu) << 11) | (2047u - idx);
            if (pk >= cutN) wN = true;
        }
        if (!wP) lp += px;
        if (!wN) ln += nx;
    }
    #pragma unroll
    for (int off = 32; off; off >>= 1) {
        lp += __shfl_down(lp, off);
        ln += __shfl_down(ln, off);
    }
    if (lane == 0) { redf[wid] = lp; redf[2 + wid] = ln; }
    __syncthreads();
    const float Ptmp = FACTOR * (redf[0] + redf[1]);
    const float Ntmp = FACTOR * (redf[2] + redf[3]);

    // ---- output (nontemporal: don't evict the input from L3) ----
    v4f* pout = (v4f*)(out + rowbase);
    #pragma unroll
    for (int q = 0; q < 4; ++q) {
        v4f o;
        #pragma unroll
        for (int r = 0; r < 4; ++r) {
            const int e = 4 * q + r;
            const float px = fmaxf(xv[e], 0.f);
            const float nx = px - xv[e];
            const unsigned idx = (unsigned)((tid << 4) | e);
            bool wP = (u[e] >= thrP);
            bool wN = (u[e] <  thrN);
            if (u[e] - tieLoP < tieLenP) {
                unsigned pk = ((u[e] & 0x1FFFFFu) << 11) | (2047u - idx);
                if (pk >= cutP) wP = true;
            }
            if (u[e] - tieLoN < tieLenN) {
                unsigned pk = (((~u[e]) & 0x1FFFFFu) << 11) | (2047u - idx);
                if (pk >= cutN) wN = true;
            }
            float v = wP ? (px + Ptmp) : 0.f;
            v -= wN ? (nx + Ntmp) : 0.f;
            o[r] = v;
        }
        __builtin_nontemporal_store(o, pout + 4 * tid + q);
    }
}

extern "C" void kernel_launch(void* const* d_in, const int* in_sizes, int n_in,
                              void* d_out, int out_size, void* d_ws, size_t ws_size,
                              hipStream_t stream)
{
    const float* x = (const float*)d_in[0];
    float* out = (float*)d_out;
    (void)in_sizes; (void)n_in; (void)d_ws; (void)ws_size; (void)out_size;
    kcomp_kernel<<<NROWS, TPB, 0, stream>>>(x, out);
}

// Round 5
// 81.742 us; speedup vs baseline: 3.1690x; 3.1690x over previous
//
#include <hip/hip_runtime.h>

#define NROWS  16384
#define DIM    2048
#define KSEL   64          // TOPK/2 per side
#define FACTOR 6.26f
#define CAP    256         // per-side tie-candidate capacity (tie bin ~50, huge margin)
#define TPB    256

// Monotone order-preserving float->uint transform:
// ascending x  <=>  ascending u ; all negatives < all positives.
__device__ __forceinline__ unsigned f2ord(float f) {
    unsigned b = __float_as_uint(f);
    unsigned m = ((unsigned)((int)b >> 31)) | 0x80000000u;
    return b ^ m;
}

__global__ __launch_bounds__(TPB)
void kcomp_kernel(const float* __restrict__ xin, float* __restrict__ out)
{
    __shared__ unsigned hist32[1024];   // 2048 u16 bins packed in pairs (4 KB)
    __shared__ unsigned cand[2][CAP];   // packed (keyLow21<<11)|(2047-idx)
    __shared__ int      cnt[2];
    __shared__ int      shd[8];         // P: D,need,eqc,cut @0..3 ; N: @4..7
    __shared__ unsigned wsum[4];
    __shared__ float    redf[8];

    const int tid  = threadIdx.x;
    const int lane = tid & 63;
    const int wid  = tid >> 6;
    const size_t rowbase = (size_t)blockIdx.x * DIM;
    const float4* pin = (const float4*)(xin + rowbase);

    // thread t owns consecutive elements [8t, 8t+8)
    float4 va = pin[2 * tid];
    float4 vb = pin[2 * tid + 1];
    float xv[8] = {va.x, va.y, va.z, va.w, vb.x, vb.y, vb.z, vb.w};
    unsigned u[8];
    #pragma unroll
    for (int e = 0; e < 8; ++e) u[e] = f2ord(xv[e]);

    // ---- clear ----
    ((uint4*)hist32)[tid] = (uint4){0u, 0u, 0u, 0u};
    if (tid < 2) cnt[tid] = 0;
    if (tid < 8) shd[tid] = 0;
    __syncthreads();

    // ---- single histogram pass: 11-bit digit (u>>21), serves BOTH sides ----
    #pragma unroll
    for (int e = 0; e < 8; ++e) {
        unsigned d = u[e] >> 21;
        atomicAdd(&hist32[d >> 1], 1u << ((d & 1u) << 4));
    }
    __syncthreads();

    // ---- scan: thread t owns bins [8t,8t+8) = words [4t,4t+4) ----
    uint4 hv = ((const uint4*)hist32)[tid];
    unsigned L =
        (hv.x & 0xffffu) + (hv.x >> 16) + (hv.y & 0xffffu) + (hv.y >> 16) +
        (hv.z & 0xffffu) + (hv.z >> 16) + (hv.w & 0xffffu) + (hv.w >> 16);
    unsigned sc = L;
    #pragma unroll
    for (int off = 1; off < 64; off <<= 1) {
        unsigned v = __shfl_up(sc, off);
        if (lane >= off) sc += v;
    }
    if (lane == 63) wsum[wid] = sc;
    __syncthreads();
    unsigned base = sc - L;
    #pragma unroll
    for (int w = 0; w < 4; ++w) if (w < wid) base += wsum[w];

    // ---- crossing walk: only the straddling thread(s) ----
    {
        const unsigned TN = KSEL;               // bottom-64 crossing
        const unsigned TP = DIM - KSEL + 1;     // top-64 crossing (1985)
        const unsigned hiB = base + L;
        if ((base < TN && TN <= hiB) || (base < TP && TP <= hiB)) {
            unsigned w[4] = {hv.x, hv.y, hv.z, hv.w};
            unsigned acc = base;
            #pragma unroll
            for (int i = 0; i < 8; ++i) {
                unsigned h = (i & 1) ? (w[i >> 1] >> 16) : (w[i >> 1] & 0xffffu);
                unsigned acc2 = acc + h;
                if (acc < TN && TN <= acc2) { shd[4] = (tid << 3) | i; shd[5] = (int)(TN - acc);        shd[6] = (int)h; }
                if (acc < TP && TP <= acc2) { shd[0] = (tid << 3) | i; shd[1] = (int)(acc2 - (TP - 1)); shd[2] = (int)h; }
                acc = acc2;
            }
        }
    }
    __syncthreads();
    const int Dp = shd[0], needP = shd[1], eqcP = shd[2];
    const int Dn = shd[4], needN = shd[5], eqcN = shd[6];
    const bool fastP = (eqcP == needP);
    const bool fastN = (eqcN == needN);
    const unsigned tieLoP = (unsigned)Dp << 21;
    const unsigned tieLoN = (unsigned)Dn << 21;
    unsigned long long h64;
    h64 = ((unsigned long long)(Dp + 1)) << 21;
    const unsigned hiP = (h64 > 0xFFFFFFFFull) ? 0xFFFFFFFFu : (unsigned)h64;
    h64 = ((unsigned long long)(Dn + 1)) << 21;
    const unsigned hiN = (h64 > 0xFFFFFFFFull) ? 0xFFFFFFFFu : (unsigned)h64;
    const unsigned thrP = fastP ? tieLoP : hiP;      // plain winners: u >= thrP
    const unsigned thrN = fastN ? hiN   : tieLoN;    // plain winners: u <  thrN
    const unsigned tieLenP = fastP ? 0u : 0x200000u;
    const unsigned tieLenN = fastN ? 0u : 0x200000u;

    // ---- gather tie candidates (packed keys unique -> exact lowest-index tie-break) ----
    #pragma unroll
    for (int e = 0; e < 8; ++e) {
        const unsigned idx = (unsigned)((tid << 3) | e);
        if (u[e] - tieLoP < tieLenP) {
            int s = atomicAdd(&cnt[0], 1);
            if (s < CAP) cand[0][s] = ((u[e] & 0x1FFFFFu) << 11) | (2047u - idx);
        }
        if (u[e] - tieLoN < tieLenN) {
            int s = atomicAdd(&cnt[1], 1);
            if (s < CAP) cand[1][s] = (((~u[e]) & 0x1FFFFFu) << 11) | (2047u - idx);
        }
    }
    __syncthreads();

    // ---- rank: wave0 -> P, wave1 -> N; publish the need-th largest as cut ----
    if (wid < 2) {
        const int side = wid;
        const bool fast = side ? fastN : fastP;
        if (!fast) {
            const int eqc  = side ? eqcN : eqcP;
            const int need = side ? needN : needP;
            const int ec   = min(eqc, CAP);
            for (int j = lane; j < ec; j += 64) {
                const unsigned mine = cand[side][j];
                int rank = 0;
                for (int s = 0; s < ec; ++s)      // broadcast LDS reads
                    rank += (cand[side][s] > mine);
                if (rank == need - 1) shd[side ? 7 : 3] = (int)mine;
            }
        }
    }
    __syncthreads();
    const unsigned cutP = (unsigned)shd[3];
    const unsigned cutN = (unsigned)shd[7];

    // ---- classify + loser energy (fused) ----
    unsigned winP = 0, winN = 0;
    float lp = 0.f, ln = 0.f;
    #pragma unroll
    for (int e = 0; e < 8; ++e) {
        const unsigned idx = (unsigned)((tid << 3) | e);
        bool wP = (u[e] >= thrP);
        bool wN = (u[e] <  thrN);
        if (u[e] - tieLoP < tieLenP) {
            unsigned pk = ((u[e] & 0x1FFFFFu) << 11) | (2047u - idx);
            if (pk >= cutP) wP = true;
        }
        if (u[e] - tieLoN < tieLenN) {
            unsigned pk = (((~u[e]) & 0x1FFFFFu) << 11) | (2047u - idx);
            if (pk >= cutN) wN = true;
        }
        if (wP) winP |= 1u << e;
        if (wN) winN |= 1u << e;
        const float px = fmaxf(xv[e], 0.f);
        const float nx = px - xv[e];             // == fmaxf(-x, 0)
        if (!wP) lp += px;
        if (!wN) ln += nx;
    }
    #pragma unroll
    for (int off = 32; off; off >>= 1) {
        lp += __shfl_down(lp, off);
        ln += __shfl_down(ln, off);
    }
    if (lane == 0) { redf[wid] = lp; redf[4 + wid] = ln; }
    __syncthreads();
    const float Ptmp = FACTOR * (redf[0] + redf[1] + redf[2] + redf[3]);
    const float Ntmp = FACTOR * (redf[4] + redf[5] + redf[6] + redf[7]);

    // ---- output (regular cached stores) ----
    float o[8];
    #pragma unroll
    for (int e = 0; e < 8; ++e) {
        const float px = fmaxf(xv[e], 0.f);
        const float nx = px - xv[e];
        float v = ((winP >> e) & 1u) ? (px + Ptmp) : 0.f;
        v -= ((winN >> e) & 1u) ? (nx + Ntmp) : 0.f;
        o[e] = v;
    }
    float4* pout = (float4*)(out + rowbase);
    float4 o0 = {o[0], o[1], o[2], o[3]};
    float4 o1 = {o[4], o[5], o[6], o[7]};
    pout[2 * tid]     = o0;
    pout[2 * tid + 1] = o1;
}

extern "C" void kernel_launch(void* const* d_in, const int* in_sizes, int n_in,
                              void* d_out, int out_size, void* d_ws, size_t ws_size,
                              hipStream_t stream)
{
    const float* x = (const float*)d_in[0];
    float* out = (float*)d_out;
    (void)in_sizes; (void)n_in; (void)d_ws; (void)ws_size; (void)out_size;
    kcomp_kernel<<<NROWS, TPB, 0, stream>>>(x, out);
}